// Round 1
// baseline (677.352 us; speedup 1.0000x reference)
//
#include <hip/hip_runtime.h>
#include <stdint.h>

typedef __bf16 bf16x8 __attribute__((ext_vector_type(8)));
typedef float f32x4 __attribute__((ext_vector_type(4)));

constexpr int NB = 8;      // batch
constexpr int NC = 256;    // channels C
constexpr int NN = 2048;   // sequence N
constexpr int NH = 4;      // heads
constexpr int ND = 64;     // head dim
constexpr int NC2 = 512;   // 2C

__device__ __forceinline__ ushort f2bf(float f) {
  union { float f; uint32_t u; } x; x.f = f;
  return (ushort)((x.u + 0x7FFFu + ((x.u >> 16) & 1u)) >> 16);
}
__device__ __forceinline__ float bf2f(ushort h) {
  union { uint32_t u; float f; } x; x.u = (uint32_t)h << 16;
  return x.f;
}

// ---------------- small prep kernels ----------------

__global__ void k_cast(const float* __restrict__ s, ushort* __restrict__ d, int n) {
  int i = blockIdx.x * 256 + threadIdx.x;
  if (i < n) d[i] = f2bf(s[i]);
}

// Wm with columns permuted to head-major: dst[co][h*64+d] = Wm[co][d*4+h]
__global__ void k_cast_wm_perm(const float* __restrict__ s, ushort* __restrict__ d) {
  int i = blockIdx.x * 256 + threadIdx.x;   // 65536
  int co = i >> 8, j = i & 255;
  int h = j >> 6, dd = j & 63;
  d[i] = f2bf(s[co * NC + dd * NH + h]);
}

// X [b][C][N] f32 -> XT [b][N][C] bf16
__global__ void k_transpose_cast(const float* __restrict__ s, ushort* __restrict__ d) {
  int n = blockIdx.x * 256 + threadIdx.x;
  int c0 = blockIdx.y * 8;
  int b = blockIdx.z;
  const float* p = s + ((size_t)b * NC + c0) * NN + n;
  union { ushort u[8]; uint4 v; } t;
#pragma unroll
  for (int i = 0; i < 8; ++i) t.u[i] = f2bf(p[(size_t)i * NN]);
  *(uint4*)(d + ((size_t)b * NN + n) * NC + c0) = t.v;
}

// q_nat [b][d*4+h][n] bf16 -> qt [(b*4+h)][n][d] bf16
__global__ void k_head_transpose(const ushort* __restrict__ s, ushort* __restrict__ d) {
  int n = blockIdx.x * 256 + threadIdx.x;
  int d0 = blockIdx.y * 8;
  int z = blockIdx.z, b = z >> 2, h = z & 3;
  const ushort* p = s + ((size_t)b * NC + (size_t)d0 * NH + h) * NN + n;
  union { ushort u[8]; uint4 v; } t;
#pragma unroll
  for (int i = 0; i < 8; ++i) t.u[i] = p[(size_t)i * NH * NN];
  *(uint4*)(d + ((size_t)z * NN + n) * ND + d0) = t.v;
}

// row softmax in place, one block per row of 2048 f32
__global__ __launch_bounds__(256) void k_softmax(float* __restrict__ attn) {
  size_t row = blockIdx.x;
  float* p = attn + row * NN;
  int t = threadIdx.x;
  float4 v0 = ((const float4*)p)[t * 2];
  float4 v1 = ((const float4*)p)[t * 2 + 1];
  float m = fmaxf(fmaxf(fmaxf(v0.x, v0.y), fmaxf(v0.z, v0.w)),
                  fmaxf(fmaxf(v1.x, v1.y), fmaxf(v1.z, v1.w)));
#pragma unroll
  for (int o = 1; o < 64; o <<= 1) m = fmaxf(m, __shfl_xor(m, o));
  __shared__ float red[4], red2[4];
  if ((t & 63) == 0) red[t >> 6] = m;
  __syncthreads();
  m = fmaxf(fmaxf(red[0], red[1]), fmaxf(red[2], red[3]));
  float e[8];
  e[0] = __expf(v0.x - m); e[1] = __expf(v0.y - m); e[2] = __expf(v0.z - m); e[3] = __expf(v0.w - m);
  e[4] = __expf(v1.x - m); e[5] = __expf(v1.y - m); e[6] = __expf(v1.z - m); e[7] = __expf(v1.w - m);
  float sum = e[0]+e[1]+e[2]+e[3]+e[4]+e[5]+e[6]+e[7];
#pragma unroll
  for (int o = 1; o < 64; o <<= 1) sum += __shfl_xor(sum, o);
  if ((t & 63) == 0) red2[t >> 6] = sum;
  __syncthreads();
  sum = red2[0] + red2[1] + red2[2] + red2[3];
  float inv = 1.f / sum;
  ((float4*)p)[t * 2]     = make_float4(e[0]*inv, e[1]*inv, e[2]*inv, e[3]*inv);
  ((float4*)p)[t * 2 + 1] = make_float4(e[4]*inv, e[5]*inv, e[6]*inv, e[7]*inv);
}

__global__ void k_bn_finalize(const float* __restrict__ stats, const float* __restrict__ gamma,
                              const float* __restrict__ beta, float4* __restrict__ aff) {
  int c = blockIdx.x * 256 + threadIdx.x;
  if (c >= NC2) return;
  const float inv_n = 1.f / (float)(NB * NN);
  float mu  = stats[c * 2] * inv_n;
  float var = stats[c * 2 + 1] * inv_n - mu * mu;
  float isg = gamma[c] * rsqrtf(var + 1e-5f);
  aff[c] = make_float4(mu, isg, beta[c], 0.f);
}

// ---------------- generic MFMA GEMM: D[r][c] = sum_k A[r][k]*B[c][k] ----------------
// All operands staged as bf16 [rows][64k] tiles in LDS (row pad to 72 elems).
// frag read: lane holds row (lane&15), k = ks*32 + (lane>>4)*8 .. +8 (contiguous).

enum GemmMode { M_PROJ = 0, M_SCORES, M_PV, M_WM, M_W1, M_W2 };

template <int MODE>
__global__ __launch_bounds__(256) void k_gemm(
    const ushort* __restrict__ A, const ushort* __restrict__ A2,
    const float* __restrict__ Af, const ushort* __restrict__ Bm,
    const float* __restrict__ bias, const float4* __restrict__ aff,
    float* __restrict__ stats, float* __restrict__ outf, ushort* __restrict__ outb) {
  constexpr int BR = 128;
  constexpr int BC = (MODE == M_PV) ? 64 : 128;
  constexpr int KT = (MODE == M_SCORES) ? 64 : (MODE == M_PV) ? 2048
                   : (MODE == M_PROJ || MODE == M_WM) ? 256 : 512;
  constexpr int FR = 4;
  constexpr int FC = BC / 32;
  constexpr int LDL = 72;

  __shared__ ushort ldsA[BR * LDL];
  __shared__ ushort ldsB[BC * LDL];

  const int tid = threadIdx.x;
  const int lane = tid & 63, wave = tid >> 6;
  const int wr = (wave >> 1) * (FR * 16), wc = (wave & 1) * (FC * 16);
  const int lr = lane & 15, lk = (lane >> 4) * 8;
  const int c0 = blockIdx.x * BC, r0 = blockIdx.y * BR;
  const size_t z = blockIdx.z;

  f32x4 acc[FR][FC] = {};

  for (int kk = 0; kk < KT; kk += 64) {
    // ---- stage A: BR rows x 64 k ----
    if constexpr (MODE == M_PV) {
      const float* src = Af + (z * NN + r0) * (size_t)NN + kk;
#pragma unroll
      for (int i = 0; i < BR / 32; ++i) {
        int off = (tid + i * 256) * 8, row = off >> 6, k = off & 63;
        const float* q = src + (size_t)row * NN + k;
        float4 x0 = *(const float4*)q, x1 = *(const float4*)(q + 4);
        union { ushort u[8]; uint4 v; } t;
        t.u[0] = f2bf(x0.x); t.u[1] = f2bf(x0.y); t.u[2] = f2bf(x0.z); t.u[3] = f2bf(x0.w);
        t.u[4] = f2bf(x1.x); t.u[5] = f2bf(x1.y); t.u[6] = f2bf(x1.z); t.u[7] = f2bf(x1.w);
        *(uint4*)&ldsA[row * LDL + k] = t.v;
      }
    } else {
      const ushort* src; int ld;
      if constexpr (MODE == M_PROJ)        { src = A + (size_t)r0 * NC + kk; ld = NC; }
      else if constexpr (MODE == M_SCORES) { src = A + (z * NN + r0) * (size_t)ND + kk; ld = ND; }
      else if constexpr (MODE == M_WM)     { src = A + (z * NN + r0) * (size_t)NC + kk; ld = NC; }
      else if constexpr (MODE == M_W1) {
        if (kk < NC) src = A  + (z * NN + r0) * (size_t)NC + kk;
        else         src = A2 + (z * NN + r0) * (size_t)NC + (kk - NC);
        ld = NC;
      } else { src = A + (size_t)r0 * NC2 + kk; ld = NC2; }   // M_W2
#pragma unroll
      for (int i = 0; i < BR / 32; ++i) {
        int off = (tid + i * 256) * 8, row = off >> 6, k = off & 63;
        *(uint4*)&ldsA[row * LDL + k] = *(const uint4*)(src + (size_t)row * ld + k);
      }
    }
    // ---- stage B: BC rows x 64 k ----
    if constexpr (MODE == M_W2) {
      // hT rows (n), with fused BN affine + LeakyReLU
      const ushort* src = Bm + (z * NN + c0) * (size_t)NC2 + kk;
#pragma unroll
      for (int i = 0; i < BC / 32; ++i) {
        int off = (tid + i * 256) * 8, row = off >> 6, k = off & 63;
        union { ushort u[8]; uint4 v; } t, o;
        t.v = *(const uint4*)(src + (size_t)row * NC2 + k);
#pragma unroll
        for (int e = 0; e < 8; ++e) {
          float4 pr = aff[kk + k + e];
          float y = (bf2f(t.u[e]) - pr.x) * pr.y + pr.z;
          y = y > 0.f ? y : 0.2f * y;
          o.u[e] = f2bf(y);
        }
        *(uint4*)&ldsB[row * LDL + k] = o.v;
      }
    } else {
      const ushort* src; int ld;
      if constexpr (MODE == M_PROJ)        { src = Bm + (z * NN + c0) * (size_t)NC + kk; ld = NC; }
      else if constexpr (MODE == M_SCORES) { src = Bm + (z * NN + c0) * (size_t)ND + kk; ld = ND; }
      else if constexpr (MODE == M_PV)     { src = Bm + ((z >> 2) * NC + (z & 3)) * (size_t)NN + (size_t)c0 * 4 * NN + kk; ld = 4 * NN; }
      else if constexpr (MODE == M_WM)     { src = Bm + (size_t)c0 * NC + kk; ld = NC; }
      else                                  { src = Bm + (size_t)c0 * NC2 + kk; ld = NC2; }  // M_W1
#pragma unroll
      for (int i = 0; i < BC / 32; ++i) {
        int off = (tid + i * 256) * 8, row = off >> 6, k = off & 63;
        *(uint4*)&ldsB[row * LDL + k] = *(const uint4*)(src + (size_t)row * ld + k);
      }
    }
    __syncthreads();
#pragma unroll
    for (int ks = 0; ks < 2; ++ks) {
      bf16x8 afr[FR], bfr[FC];
#pragma unroll
      for (int fr = 0; fr < FR; ++fr)
        afr[fr] = *(const bf16x8*)&ldsA[(wr + fr * 16 + lr) * LDL + ks * 32 + lk];
#pragma unroll
      for (int fc = 0; fc < FC; ++fc)
        bfr[fc] = *(const bf16x8*)&ldsB[(wc + fc * 16 + lr) * LDL + ks * 32 + lk];
#pragma unroll
      for (int fr = 0; fr < FR; ++fr)
#pragma unroll
        for (int fc = 0; fc < FC; ++fc)
          acc[fr][fc] = __builtin_amdgcn_mfma_f32_16x16x32_bf16(afr[fr], bfr[fc], acc[fr][fc], 0, 0, 0);
    }
    __syncthreads();
  }

  // ---- epilogue: D row=(lane>>4)*4+j, col=lane&15 within each 16x16 frag ----
  float sfc[FC], qfc[FC];
#pragma unroll
  for (int fc = 0; fc < FC; ++fc) { sfc[fc] = 0.f; qfc[fc] = 0.f; }
#pragma unroll
  for (int fr = 0; fr < FR; ++fr)
#pragma unroll
    for (int fc = 0; fc < FC; ++fc)
#pragma unroll
      for (int j = 0; j < 4; ++j) {
        int r = r0 + wr + fr * 16 + (lane >> 4) * 4 + j;
        int c = c0 + wc + fc * 16 + lr;
        float v = acc[fr][fc][j];
        if constexpr (MODE == M_PROJ) {
          v += bias[r];
          outb[(z * NC + r) * (size_t)NN + c] = f2bf(v);
        } else if constexpr (MODE == M_SCORES) {
          outf[(z * NN + r) * (size_t)NN + c] = v * 0.125f;
        } else if constexpr (MODE == M_PV) {
          outb[((z >> 2) * NN + r) * (size_t)NC + (z & 3) * ND + c] = f2bf(v);
        } else if constexpr (MODE == M_WM) {
          v += bias[c];
          outb[(z * NN + r) * (size_t)NC + c] = f2bf(v);
        } else if constexpr (MODE == M_W1) {
          v += bias[c];
          outb[(z * NN + r) * (size_t)NC2 + c] = f2bf(v);
          sfc[fc] += v; qfc[fc] += v * v;
        } else {  // M_W2
          v += bias[r];
          outf[(z * NC + r) * (size_t)NN + c] = v;
        }
      }
  if constexpr (MODE == M_W1) {
#pragma unroll
    for (int fc = 0; fc < FC; ++fc) {
      float s1 = sfc[fc], s2 = qfc[fc];
      s1 += __shfl_xor(s1, 16); s1 += __shfl_xor(s1, 32);
      s2 += __shfl_xor(s2, 16); s2 += __shfl_xor(s2, 32);
      if (lane < 16) {
        int ch = c0 + wc + fc * 16 + lane;
        atomicAdd(&stats[ch * 2],     s1);
        atomicAdd(&stats[ch * 2 + 1], s2);
      }
    }
  }
}

// ---------------- launch ----------------

extern "C" void kernel_launch(void* const* d_in, const int* in_sizes, int n_in,
                              void* d_out, int out_size, void* d_ws, size_t ws_size,
                              hipStream_t stream) {
  const float* iq    = (const float*)d_in[0];
  const float* keyi  = (const float*)d_in[1];
  const float* vali  = (const float*)d_in[2];
  const float* Wq = (const float*)d_in[3];  const float* bq = (const float*)d_in[4];
  const float* Wk = (const float*)d_in[5];  const float* bk = (const float*)d_in[6];
  const float* Wv = (const float*)d_in[7];  const float* bv = (const float*)d_in[8];
  const float* Wm = (const float*)d_in[9];  const float* bm = (const float*)d_in[10];
  const float* W1 = (const float*)d_in[11]; const float* b1 = (const float*)d_in[12];
  const float* gamma = (const float*)d_in[13]; const float* beta = (const float*)d_in[14];
  const float* W2 = (const float*)d_in[15]; const float* b2 = (const float*)d_in[16];

  float* out  = (float*)d_out;
  float* attn = out + (size_t)NB * NC * NN;   // [B,H,N,N] f32

  uint8_t* cur = (uint8_t*)d_ws;
  auto alloc = [&](size_t bytes) { uint8_t* p = cur; cur += (bytes + 255) & ~(size_t)255; return p; };
  ushort* wq_b = (ushort*)alloc((size_t)NC * NC * 2);
  ushort* wk_b = (ushort*)alloc((size_t)NC * NC * 2);
  ushort* wv_b = (ushort*)alloc((size_t)NC * NC * 2);
  ushort* wm_b = (ushort*)alloc((size_t)NC * NC * 2);
  ushort* w1_b = (ushort*)alloc((size_t)NC2 * NC2 * 2);
  ushort* w2_b = (ushort*)alloc((size_t)NC * NC2 * 2);
  const size_t TN = (size_t)NB * NN * NC;
  ushort* iqT   = (ushort*)alloc(TN * 2);  // init_query^T  [b][n][c]
  ushort* kT    = (ushort*)alloc(TN * 2);
  ushort* vT    = (ushort*)alloc(TN * 2);
  ushort* q_nat = (ushort*)alloc(TN * 2);  // [b][c][n]
  ushort* k_nat = (ushort*)alloc(TN * 2);
  ushort* v_nat = (ushort*)alloc(TN * 2);
  ushort* qt    = (ushort*)alloc(TN * 2);  // [(b h)][n][d]
  ushort* kt    = (ushort*)alloc(TN * 2);
  ushort* xT    = (ushort*)alloc(TN * 2);  // attn@V, [b][n][h*64+d]
  ushort* xmT   = (ushort*)alloc(TN * 2);  // merge out^T [b][n][co]
  ushort* hT    = (ushort*)alloc((size_t)NB * NN * NC2 * 2);
  float*  stats = (float*)alloc(NC2 * 2 * 4);
  float4* aff   = (float4*)alloc(NC2 * 16);

  hipMemsetAsync(stats, 0, NC2 * 2 * 4, stream);

  k_cast<<<dim3(256), 256, 0, stream>>>(Wq, wq_b, NC * NC);
  k_cast<<<dim3(256), 256, 0, stream>>>(Wk, wk_b, NC * NC);
  k_cast<<<dim3(256), 256, 0, stream>>>(Wv, wv_b, NC * NC);
  k_cast_wm_perm<<<dim3(256), 256, 0, stream>>>(Wm, wm_b);
  k_cast<<<dim3(1024), 256, 0, stream>>>(W1, w1_b, NC2 * NC2);
  k_cast<<<dim3(512), 256, 0, stream>>>(W2, w2_b, NC * NC2);

  k_transpose_cast<<<dim3(8, 32, 8), 256, 0, stream>>>(iq,   iqT);
  k_transpose_cast<<<dim3(8, 32, 8), 256, 0, stream>>>(keyi, kT);
  k_transpose_cast<<<dim3(8, 32, 8), 256, 0, stream>>>(vali, vT);

  k_gemm<M_PROJ><<<dim3(16, 2, 8), 256, 0, stream>>>(wq_b, nullptr, nullptr, iqT, bq, nullptr, nullptr, nullptr, q_nat);
  k_gemm<M_PROJ><<<dim3(16, 2, 8), 256, 0, stream>>>(wk_b, nullptr, nullptr, kT,  bk, nullptr, nullptr, nullptr, k_nat);
  k_gemm<M_PROJ><<<dim3(16, 2, 8), 256, 0, stream>>>(wv_b, nullptr, nullptr, vT,  bv, nullptr, nullptr, nullptr, v_nat);

  k_head_transpose<<<dim3(8, 8, 32), 256, 0, stream>>>(q_nat, qt);
  k_head_transpose<<<dim3(8, 8, 32), 256, 0, stream>>>(k_nat, kt);

  k_gemm<M_SCORES><<<dim3(16, 16, 32), 256, 0, stream>>>(qt, nullptr, nullptr, kt, nullptr, nullptr, nullptr, attn, nullptr);

  k_softmax<<<dim3(NB * NH * NN), 256, 0, stream>>>(attn);

  k_gemm<M_PV><<<dim3(1, 16, 32), 256, 0, stream>>>(nullptr, nullptr, attn, v_nat, nullptr, nullptr, nullptr, nullptr, xT);

  k_gemm<M_WM><<<dim3(2, 16, 8), 256, 0, stream>>>(xT, nullptr, nullptr, wm_b, bm, nullptr, nullptr, nullptr, xmT);

  k_gemm<M_W1><<<dim3(4, 16, 8), 256, 0, stream>>>(xmT, iqT, nullptr, w1_b, b1, nullptr, stats, nullptr, hT);

  k_bn_finalize<<<dim3(2), 256, 0, stream>>>(stats, gamma, beta, aff);

  k_gemm<M_W2><<<dim3(16, 2, 8), 256, 0, stream>>>(w2_b, nullptr, nullptr, hT, b2, aff, nullptr, out, nullptr);
}